// Round 6
// baseline (390.703 us; speedup 1.0000x reference)
//
#include <hip/hip_runtime.h>
#include <cstdint>
#include <cstddef>

typedef int   v4i   __attribute__((ext_vector_type(4)));
typedef float v4f   __attribute__((ext_vector_type(4)));
typedef __bf16 bf16x8 __attribute__((ext_vector_type(8)));
typedef __bf16 bf16x2 __attribute__((ext_vector_type(2)));

__device__ __forceinline__ float bf2f(unsigned short u) {
    union { unsigned int i; float f; } v; v.i = ((unsigned int)u) << 16; return v.f;
}
__device__ __forceinline__ unsigned short f2bf(float f) {
    union { float f; unsigned int i; } v; v.f = f;
    unsigned int r = (v.i + 0x7fffu + ((v.i >> 16) & 1u)) >> 16;
    return (unsigned short)r;
}
__device__ __forceinline__ float asf(unsigned int i) {
    union { unsigned int i; float f; } v; v.i = i; return v.f;
}
__device__ __forceinline__ float fsig(float x) {
    float e = __builtin_amdgcn_exp2f(-1.4426950408889634f * x);
    return __builtin_amdgcn_rcpf(1.0f + e);
}
// tanh(x) = 2*sigmoid(2x)-1 : saturates correctly without clamps
__device__ __forceinline__ float ftanh(float x) {
    float e = __builtin_amdgcn_exp2f(-2.8853900817779268f * x);
    return 2.0f * __builtin_amdgcn_rcpf(1.0f + e) - 1.0f;
}

// async global->LDS, 16B per lane, dest = wave-uniform base + lane*16
__device__ __forceinline__ void gload_lds16(const void* g, void* l) {
    __builtin_amdgcn_global_load_lds(
        (const __attribute__((address_space(1))) unsigned int*)(g),
        (__attribute__((address_space(3))) unsigned int*)(l),
        16, 0, 0);
}

#define QW (127.0f / 0.3f)

// k-permutation (involution): swap bits[3:2] <-> bits[1:0] of a 0..255 index
__device__ __forceinline__ int kperm(int k) {
    return (k & ~15) | ((k & 3) << 2) | ((k >> 2) & 3);
}

// ---------------- prep: weight conversions + i8 weight frag packing ----------------
__global__ __launch_bounds__(256) void prep_kernel(
    const float* __restrict__ Wih,
    const float* __restrict__ Whh, const float* __restrict__ bih,
    const float* __restrict__ bhh, const float* __restrict__ fcW,
    signed char* __restrict__ w8,
    unsigned short* __restrict__ bperm, float* __restrict__ biasp,
    unsigned short* __restrict__ fcwbf)
{
    const int NTOT = 262144 + 262144 + 1024 + 65536;
    const int stride = gridDim.x * blockDim.x;
    for (int i = blockIdx.x * blockDim.x + threadIdx.x; i < NTOT; i += stride) {
        if (i < 262144) {
            int t = i;
            int j = t & 15, lane = (t >> 4) & 63, kap = (t >> 10) & 3, tau = (t >> 12) & 3, wv = (t >> 14) & 15;
            int mloc = lane & 15, qm = mloc >> 2, gate = mloc & 3;
            int um = wv * 16 + tau * 4 + qm;
            int kpos = kap * 64 + (lane >> 4) * 16 + j;
            int uk = kperm(kpos);
            float val = Whh[(gate * 256 + um) * 256 + uk];
            int qi = (int)rintf(val * QW);
            qi = qi < -127 ? -127 : (qi > 127 ? 127 : qi);
            w8[t] = (signed char)qi;
        } else if (i < 524288) {
            int t = i - 262144;
            int nn = t >> 8, k = t & 255;
            int gate = nn & 3, tau = (nn >> 2) & 3, quad = (nn >> 4) & 3, wv = nn >> 6;
            int u = wv * 16 + tau * 4 + quad;
            bperm[t] = f2bf(Wih[(gate * 256 + u) * 256 + k]);
        } else if (i < 524288 + 1024) {
            int nn = i - 524288;
            int gate = nn & 3, tau = (nn >> 2) & 3, quad = (nn >> 4) & 3, wv = nn >> 6;
            int u = wv * 16 + tau * 4 + quad;
            biasp[nn] = bih[gate * 256 + u] + bhh[gate * 256 + u];
        } else {
            int t = i - (524288 + 1024);
            int n = t >> 8, k = t & 255;
            fcwbf[t] = f2bf(fcW[n * 256 + kperm(k)]);
        }
    }
}

// ---------------- gemm0: xg[t][1024] = x[t][:] @ bperm^T + biasp, bf16 out ----------
// v5: k-major LDS layouts + global_load_lds(16B) + LDS double-buffered B with
// ONE barrier per kt (implicit vmcnt drain = the needed wait). A staged once
// (f32->bf16), resident across all 4 n-passes -> x fetched exactly once.
// k-major [kq][row][16B]: gload dest (base+lane*16) matches per-lane source
// row=c*64+lane with NO swizzle; frag reads are 16 lanes x 16B stride = 2-way
// bank alias = free. Epilogue through LDS tile (aliases idle B buffer) ->
// full 512B-line stores. No reg staging -> no spill (round-2/4 lesson).
__global__ __launch_bounds__(512) void gemm_xg(
    const float* __restrict__ x, const unsigned short* __restrict__ B,
    const float* __restrict__ bias, unsigned short* __restrict__ out)
{
    __shared__ alignas(16) unsigned char As[32768];      // A bf16 k-major [32][64][16B]
    __shared__ alignas(16) unsigned char Bsb[2][32768];  // B bf16 k-major [8][256][16B] x2
    const int tid = threadIdx.x;
    const long long m0 = (long long)blockIdx.x * 64;
    const int l = tid & 63, wv = tid >> 6;               // 8 waves
    const int lane16 = l & 15, quad = l >> 4;
    const int wm = wv & 1, wn = wv >> 1;                 // 2m x 4n waves: 32x64 tiles

    // ---- prologue: stage A once (f32 -> bf16, k-major) ----
    {
        const int arow = tid >> 3, ac8 = tid & 7;        // 8 floats / thread / kt
#pragma unroll
        for (int kt = 0; kt < 4; ++kt) {
            const float* src = x + (m0 + arow) * 256 + kt * 64 + ac8 * 8;
            float4 a0 = *(const float4*)src;
            float4 a1 = *(const float4*)(src + 4);
            bf16x8 t;
            t[0] = (__bf16)a0.x; t[1] = (__bf16)a0.y; t[2] = (__bf16)a0.z; t[3] = (__bf16)a0.w;
            t[4] = (__bf16)a1.x; t[5] = (__bf16)a1.y; t[6] = (__bf16)a1.z; t[7] = (__bf16)a1.w;
            *(bf16x8*)(As + (kt * 8 + ac8) * 1024 + arow * 16) = t;
        }
    }
    // issue B(p=0, kt=0) -> Bsb[0]: wave wv covers kq=wv, lane covers row c*64+l
#define BLOAD(P, KT, BUF)                                                        \
    {                                                                            \
        _Pragma("unroll")                                                        \
        for (int c = 0; c < 4; ++c) {                                            \
            const void* g = (const unsigned char*)B +                            \
                ((size_t)((P) * 256 + c * 64 + l) * 512) + (KT) * 128 + wv * 16; \
            void* d = Bsb[BUF] + wv * 4096 + c * 1024;                           \
            gload_lds16(g, d);                                                   \
        }                                                                        \
    }
    BLOAD(0, 0, 0)

#pragma unroll 1
    for (int p = 0; p < 4; ++p) {
        const int n0 = p * 256;
        v4f acc[2][4];
#pragma unroll
        for (int a = 0; a < 2; ++a)
#pragma unroll
            for (int b = 0; b < 4; ++b) acc[a][b] = (v4f){0.f, 0.f, 0.f, 0.f};

#pragma unroll
        for (int kt = 0; kt < 4; ++kt) {
            __syncthreads();          // drains this wave's gloads (vmcnt) + syncs all
            if (kt < 3) BLOAD(p, kt + 1, (kt + 1) & 1)   // fly under MFMAs
            const unsigned char* Bcur = Bsb[kt & 1];
#pragma unroll
            for (int ks = 0; ks < 2; ++ks) {
                bf16x8 af[2], bfr[4];
#pragma unroll
                for (int mt = 0; mt < 2; ++mt)
                    af[mt] = *(const bf16x8*)(As + (kt * 8 + ks * 4 + quad) * 1024 +
                                              (wm * 32 + mt * 16 + lane16) * 16);
#pragma unroll
                for (int nt = 0; nt < 4; ++nt)
                    bfr[nt] = *(const bf16x8*)(Bcur + (ks * 4 + quad) * 4096 +
                                               (wn * 64 + nt * 16 + lane16) * 16);
#pragma unroll
                for (int mt = 0; mt < 2; ++mt)
#pragma unroll
                    for (int nt = 0; nt < 4; ++nt)
                        acc[mt][nt] = __builtin_amdgcn_mfma_f32_16x16x32_bf16(af[mt], bfr[nt], acc[mt][nt], 0, 0, 0);
            }
        }

        // ---- epilogue: acc -> Cs (aliases Bsb[1]) -> full-line global stores ----
        float bv[4];
#pragma unroll
        for (int nt = 0; nt < 4; ++nt) bv[nt] = bias[n0 + wn * 64 + nt * 16 + lane16];
        __syncthreads();              // all MFMA reads done (Bsb[1] free for Cs)
        if (p < 3) BLOAD(p + 1, 0, 0) // next-pass kt0 prefetch flies under epilogue
        unsigned short* Cs = (unsigned short*)Bsb[1];
#pragma unroll
        for (int mt = 0; mt < 2; ++mt)
#pragma unroll
            for (int nt = 0; nt < 4; ++nt)
#pragma unroll
                for (int r = 0; r < 4; ++r) {
                    int row = wm * 32 + mt * 16 + quad * 4 + r;
                    int col = wn * 64 + nt * 16 + lane16;
                    Cs[row * 256 + col] = f2bf(acc[mt][nt][r] + bv[nt]);
                }
        __syncthreads();              // Cs complete
#pragma unroll
        for (int i = 0; i < 8; ++i) {
            int g = i * 512 + tid;
            int row = g >> 6, c = g & 63;     // 64 x 8B chunks per 512B row segment
            uint2 v = *(const uint2*)((const unsigned char*)Cs + row * 512 + c * 8);
            *(uint2*)(out + (m0 + row) * 1024 + n0 + c * 4) = v;
        }
    }
#undef BLOAD
}

// ---------------- gemm1: out[t][256] = 2*sigmoid(h2b[t][:] @ fcwbf^T + fcb) ----------
// v5: same template as gemm_xg v5 — A AND B staged via global_load_lds into
// k-major LDS (A once, B double-buffered, one barrier per kt). Single n-pass
// (N=256). f32 LDS-transpose epilogue (aliases Bsb[0]) in two 32-row halves ->
// full contiguous 1KB-row stores. Accumulation order identical -> bit-exact.
__global__ __launch_bounds__(512) void gemm_fc(
    const unsigned short* __restrict__ A, const unsigned short* __restrict__ B,
    const float* __restrict__ bias, float* __restrict__ out)
{
    __shared__ alignas(16) unsigned char As[32768];      // A bf16 k-major [32][64][16B]
    __shared__ alignas(16) unsigned char Bsb[2][32768];  // B bf16 k-major [8][256][16B] x2
    const int tid = threadIdx.x;
    const long long m0 = (long long)blockIdx.x * 64;
    const int l = tid & 63, wv = tid >> 6;
    const int lane16 = l & 15, quad = l >> 4;
    const int wm = wv & 1, wn = wv >> 1;                 // 2m x 4n waves: 32x64 tiles

    // ---- prologue: A once via gload (kqa = wv*4+c, row = lane) ----
#pragma unroll
    for (int c = 0; c < 4; ++c) {
        const void* g = (const unsigned char*)A + ((size_t)(m0 + l) * 512) + (wv * 4 + c) * 16;
        void* d = As + (wv * 4 + c) * 1024 + 0;
        gload_lds16(g, d);
    }
#define BLOADF(KT, BUF)                                                          \
    {                                                                            \
        _Pragma("unroll")                                                        \
        for (int c = 0; c < 4; ++c) {                                            \
            const void* g = (const unsigned char*)B +                            \
                ((size_t)(c * 64 + l) * 512) + (KT) * 128 + wv * 16;             \
            void* d = Bsb[BUF] + wv * 4096 + c * 1024;                           \
            gload_lds16(g, d);                                                   \
        }                                                                        \
    }
    BLOADF(0, 0)

    v4f acc[2][4];
#pragma unroll
    for (int a = 0; a < 2; ++a)
#pragma unroll
        for (int b = 0; b < 4; ++b) acc[a][b] = (v4f){0.f, 0.f, 0.f, 0.f};

#pragma unroll
    for (int kt = 0; kt < 4; ++kt) {
        __syncthreads();
        if (kt < 3) BLOADF(kt + 1, (kt + 1) & 1)
        const unsigned char* Bcur = Bsb[kt & 1];
#pragma unroll
        for (int ks = 0; ks < 2; ++ks) {
            bf16x8 af[2], bfr[4];
#pragma unroll
            for (int mt = 0; mt < 2; ++mt)
                af[mt] = *(const bf16x8*)(As + (kt * 8 + ks * 4 + quad) * 1024 +
                                          (wm * 32 + mt * 16 + lane16) * 16);
#pragma unroll
            for (int nt = 0; nt < 4; ++nt)
                bfr[nt] = *(const bf16x8*)(Bcur + (ks * 4 + quad) * 4096 +
                                           (wn * 64 + nt * 16 + lane16) * 16);
#pragma unroll
            for (int mt = 0; mt < 2; ++mt)
#pragma unroll
                for (int nt = 0; nt < 4; ++nt)
                    acc[mt][nt] = __builtin_amdgcn_mfma_f32_16x16x32_bf16(af[mt], bfr[nt], acc[mt][nt], 0, 0, 0);
        }
    }

    // ---- epilogue: bias + 2*sigmoid -> Csf (f32 [32][256], aliases Bsb[0]) ----
    float bv[4];
#pragma unroll
    for (int nt = 0; nt < 4; ++nt) bv[nt] = bias[wn * 64 + nt * 16 + lane16];
    float* Csf = (float*)Bsb[0];      // kt3 read Bsb[1]; Bsb[0] idle after barrier
#pragma unroll 1
    for (int half = 0; half < 2; ++half) {
        __syncthreads();              // k-loop reads / prev-half Csf reads done
        if (wm == half) {
#pragma unroll
            for (int mt = 0; mt < 2; ++mt)
#pragma unroll
                for (int nt = 0; nt < 4; ++nt)
#pragma unroll
                    for (int r = 0; r < 4; ++r) {
                        int row = mt * 16 + quad * 4 + r;          // 0..31
                        int col = wn * 64 + nt * 16 + lane16;
                        Csf[row * 256 + col] = 2.0f * fsig(acc[mt][nt][r] + bv[nt]);
                    }
        }
        __syncthreads();              // Csf complete
#pragma unroll
        for (int i = 0; i < 4; ++i) {
            int g = i * 512 + tid;
            int row = g >> 6, c = g & 63;     // 64 int4 chunks per 1KB row
            int4 v = *(const int4*)((const unsigned char*)Csf + row * 1024 + c * 16);
            *(int4*)(out + (m0 + half * 32 + row) * 256 + c * 4) = v;
        }
    }
#undef BLOADF
}

// ---------------- chunked-parallel LSTM scan ----------------
// 256 WGs x 1024 thr. 16 chunks of 16 steps per WG as MFMA columns; burn-in 24.
// W_hh i8 frags in VGPRs; H i8 double-buffered in LDS; xg register-prefetched
// (no clamp: the one-past-end row lands in the h2b workspace region, value
// never consumed); one barrier/step; v_perm-based i8/bf16 packing.
__global__ __launch_bounds__(1024) void lstm_scan(
    const signed char* __restrict__ wfrag, const unsigned short* __restrict__ xg,
    const float* __restrict__ h0, const float* __restrict__ c0,
    unsigned short* __restrict__ h2)
{
    __shared__ alignas(16) signed char Hl[2][16 * 272];
    const int tid = threadIdx.x;
    const int l = tid & 63, wv = tid >> 6;       // wv 0..15
    const int n = l & 15, quad = l >> 4;
    const int wg = blockIdx.x;

    v4i wf[4][4];
#pragma unroll
    for (int tau = 0; tau < 4; ++tau)
#pragma unroll
        for (int kap = 0; kap < 4; ++kap)
            wf[tau][kap] = *(const v4i*)(wfrag + ((((wv * 4 + tau) * 4 + kap) * 64 + l) << 4));

    const int cs0 = (wg * 16 + n) * 16;
    int start = cs0 - 24; if (start < 0) start = 0;
    float cs[4];
#pragma unroll
    for (int tau = 0; tau < 4; ++tau) {
        int u = wv * 16 + tau * 4 + quad;
        cs[tau] = (start == 0) ? c0[u] : 0.f;
    }
    for (int e = tid; e < 4096; e += 1024) {
        int cc = e >> 8, q = e & 255;
        int st = (wg * 16 + cc) * 16 - 24;
        float hv = (st <= 0) ? h0[kperm(q)] : 0.f;
        int qi = (int)rintf(hv * 127.f);
        qi = qi < -127 ? -127 : (qi > 127 ? 127 : qi);
        Hl[0][cc * 272 + q] = (signed char)qi;
    }
    __syncthreads();

    const unsigned short* xbase = xg + wv * 64 + quad * 16;
    int4 xv0, xv1;
    {
        const unsigned short* p = xbase + (long long)start * 1024;
        xv0 = *(const int4*)p;
        xv1 = *(const int4*)(p + 8);
    }

    const float SCL = (0.3f / 127.f) * (1.f / 127.f);
    for (int s = 0; s < 40; ++s) {
        const int cur = s & 1;
        const int t = start + s;
        v4i bfr[4];
#pragma unroll
        for (int kap = 0; kap < 4; ++kap)
            bfr[kap] = *(const v4i*)(Hl[cur] + n * 272 + kap * 64 + quad * 16);

        int4 xn0, xn1;
        {
            const unsigned short* p = xbase + (long long)(t + 1) * 1024;
            xn0 = *(const int4*)p;
            xn1 = *(const int4*)(p + 8);
        }

        const bool wr = ((unsigned)(t - cs0) < 16u);
        unsigned int qlo = 0, qhi = 0;      // packed i8 bytes (pairs)
        unsigned int blo = 0, bhi = 0;      // packed bf16 pairs
        int qprev = 0; float hprev = 0.f;
        int xw[8] = { xv0.x, xv0.y, xv0.z, xv0.w, xv1.x, xv1.y, xv1.z, xv1.w };
#pragma unroll
        for (int tau = 0; tau < 4; ++tau) {
            v4i a = (v4i){0, 0, 0, 0};
#pragma unroll
            for (int kap = 0; kap < 4; ++kap)
                a = __builtin_amdgcn_mfma_i32_16x16x64_i8(wf[tau][kap], bfr[kap], a, 0, 0, 0);
            unsigned int w0 = (unsigned int)xw[tau * 2], w1 = (unsigned int)xw[tau * 2 + 1];
            float gi = fmaf((float)a[0], SCL, asf(w0 << 16));
            float gf = fmaf((float)a[1], SCL, asf(w0 & 0xffff0000u));
            float gg = fmaf((float)a[2], SCL, asf(w1 << 16));
            float go = fmaf((float)a[3], SCL, asf(w1 & 0xffff0000u));
            float ig = fsig(gi), fg = fsig(gf), og = fsig(go), gt = ftanh(gg);
            float cn = fmaf(fg, cs[tau], ig * gt);
            float hn = og * ftanh(cn);
            cs[tau] = cn;
            float qf = fminf(127.f, fmaxf(-127.f, hn * 127.f));
            int qi = (int)rintf(qf);
            if (tau == 0) { qprev = qi; hprev = hn; }
            else if (tau == 1) {
                qlo = __builtin_amdgcn_perm((unsigned int)qi, (unsigned int)qprev, 0x00000400u);
                bf16x2 p; p[0] = (__bf16)hprev; p[1] = (__bf16)hn;
                blo = __builtin_bit_cast(unsigned int, p);
            } else if (tau == 2) { qprev = qi; hprev = hn; }
            else {
                qhi = __builtin_amdgcn_perm((unsigned int)qi, (unsigned int)qprev, 0x04000000u);
                bf16x2 p; p[0] = (__bf16)hprev; p[1] = (__bf16)hn;
                bhi = __builtin_bit_cast(unsigned int, p);
            }
        }
        unsigned int hb = __builtin_amdgcn_perm(qhi, qlo, 0x07060100u);
        *(unsigned int*)(Hl[cur ^ 1] + n * 272 + wv * 16 + quad * 4) = hb;
        if (wr) {
            uint2 hw; hw.x = blo; hw.y = bhi;
            *(uint2*)(h2 + (long long)t * 256 + wv * 16 + quad * 4) = hw;
        }
        __syncthreads();
        xv0 = xn0; xv1 = xn1;
    }
}

extern "C" void kernel_launch(void* const* d_in, const int* in_sizes, int n_in,
                              void* d_out, int out_size, void* d_ws, size_t ws_size,
                              hipStream_t stream)
{
    const float* x    = (const float*)d_in[0];
    const float* Wih2 = (const float*)d_in[7];
    const float* Whh2 = (const float*)d_in[8];
    const float* bih2 = (const float*)d_in[9];
    const float* bhh2 = (const float*)d_in[10];
    const float* h02  = (const float*)d_in[11];
    const float* c02  = (const float*)d_in[12];
    const float* fcW  = (const float*)d_in[13];
    const float* fcb  = (const float*)d_in[14];

    char* ws = (char*)d_ws;
    unsigned short* xgb   = (unsigned short*)(ws);                 // 128 MB xg bf16 [T][1024]
    unsigned short* h2b   = (unsigned short*)(ws + 134217728);     // 32 MB  h2 bf16 [T][256] (k-permuted cols)
    signed char*    w8    = (signed char*)   (ws + 167772160);     // 256 KB W_hh i8 frags
    unsigned short* bperm = (unsigned short*)(ws + 168034304);     // 512 KB W_ih bf16 permuted
    float*          biasp = (float*)         (ws + 168558592);     // 4 KB   fused bias permuted
    unsigned short* fcwbf = (unsigned short*)(ws + 168562688);     // 128 KB fc_W bf16 (k-permuted)

    prep_kernel<<<dim3(1024), dim3(256), 0, stream>>>(
        Wih2, Whh2, bih2, bhh2, fcW, w8, bperm, biasp, fcwbf);

    gemm_xg<<<dim3(1024), dim3(512), 0, stream>>>(x, bperm, biasp, xgb);

    lstm_scan<<<dim3(256), dim3(1024), 0, stream>>>(w8, xgb, h02, c02, h2b);

    gemm_fc<<<dim3(1024), dim3(512), 0, stream>>>(h2b, fcwbf, fcb, (float*)d_out);
}

// Round 7
// 344.456 us; speedup vs baseline: 1.1343x; 1.1343x over previous
//
#include <hip/hip_runtime.h>
#include <cstdint>
#include <cstddef>

typedef int   v4i   __attribute__((ext_vector_type(4)));
typedef float v4f   __attribute__((ext_vector_type(4)));
typedef __bf16 bf16x8 __attribute__((ext_vector_type(8)));
typedef __bf16 bf16x2 __attribute__((ext_vector_type(2)));

__device__ __forceinline__ float bf2f(unsigned short u) {
    union { unsigned int i; float f; } v; v.i = ((unsigned int)u) << 16; return v.f;
}
__device__ __forceinline__ unsigned short f2bf(float f) {
    union { float f; unsigned int i; } v; v.f = f;
    unsigned int r = (v.i + 0x7fffu + ((v.i >> 16) & 1u)) >> 16;
    return (unsigned short)r;
}
__device__ __forceinline__ float asf(unsigned int i) {
    union { unsigned int i; float f; } v; v.i = i; return v.f;
}
__device__ __forceinline__ float fsig(float x) {
    float e = __builtin_amdgcn_exp2f(-1.4426950408889634f * x);
    return __builtin_amdgcn_rcpf(1.0f + e);
}
// tanh(x) = 2*sigmoid(2x)-1 : saturates correctly without clamps
__device__ __forceinline__ float ftanh(float x) {
    float e = __builtin_amdgcn_exp2f(-2.8853900817779268f * x);
    return 2.0f * __builtin_amdgcn_rcpf(1.0f + e) - 1.0f;
}

// async global->LDS, 16B per lane, dest = wave-uniform base + lane*16
__device__ __forceinline__ void gload_lds16(const void* g, void* l) {
    __builtin_amdgcn_global_load_lds(
        (const __attribute__((address_space(1))) unsigned int*)(g),
        (__attribute__((address_space(3))) unsigned int*)(l),
        16, 0, 0);
}

#define QW (127.0f / 0.3f)

// k-permutation (involution): swap bits[3:2] <-> bits[1:0] of a 0..255 index
__device__ __forceinline__ int kperm(int k) {
    return (k & ~15) | ((k & 3) << 2) | ((k >> 2) & 3);
}

// ---------------- prep: weight conversions + i8 weight frag packing ----------------
__global__ __launch_bounds__(256) void prep_kernel(
    const float* __restrict__ Wih,
    const float* __restrict__ Whh, const float* __restrict__ bih,
    const float* __restrict__ bhh, const float* __restrict__ fcW,
    signed char* __restrict__ w8,
    unsigned short* __restrict__ bperm, float* __restrict__ biasp,
    unsigned short* __restrict__ fcwbf)
{
    const int NTOT = 262144 + 262144 + 1024 + 65536;
    const int stride = gridDim.x * blockDim.x;
    for (int i = blockIdx.x * blockDim.x + threadIdx.x; i < NTOT; i += stride) {
        if (i < 262144) {
            int t = i;
            int j = t & 15, lane = (t >> 4) & 63, kap = (t >> 10) & 3, tau = (t >> 12) & 3, wv = (t >> 14) & 15;
            int mloc = lane & 15, qm = mloc >> 2, gate = mloc & 3;
            int um = wv * 16 + tau * 4 + qm;
            int kpos = kap * 64 + (lane >> 4) * 16 + j;
            int uk = kperm(kpos);
            float val = Whh[(gate * 256 + um) * 256 + uk];
            int qi = (int)rintf(val * QW);
            qi = qi < -127 ? -127 : (qi > 127 ? 127 : qi);
            w8[t] = (signed char)qi;
        } else if (i < 524288) {
            int t = i - 262144;
            int nn = t >> 8, k = t & 255;
            int gate = nn & 3, tau = (nn >> 2) & 3, quad = (nn >> 4) & 3, wv = nn >> 6;
            int u = wv * 16 + tau * 4 + quad;
            bperm[t] = f2bf(Wih[(gate * 256 + u) * 256 + k]);
        } else if (i < 524288 + 1024) {
            int nn = i - 524288;
            int gate = nn & 3, tau = (nn >> 2) & 3, quad = (nn >> 4) & 3, wv = nn >> 6;
            int u = wv * 16 + tau * 4 + quad;
            biasp[nn] = bih[gate * 256 + u] + bhh[gate * 256 + u];
        } else {
            int t = i - (524288 + 1024);
            int n = t >> 8, k = t & 255;
            fcwbf[t] = f2bf(fcW[n * 256 + kperm(k)]);
        }
    }
}

// ---------------- gemm0: xg[t][1024] = x[t][:] @ bperm^T + biasp, bf16 out ----------
// v6: A entirely in REGISTERS (each lane holds its row-quarter: 8x bf16x8 =
// 32 VGPR, loaded once, dense 128B-line footprint), B via global_load_lds into
// k-major double-buffered LDS (64KB total -> 2 blocks/CU, the occupancy v5
// lost at 96KB). One barrier per kt (implicit vmcnt drain). 4m x 2n waves:
// 16x128 per wave. Full-line epilogue through LDS (aliases Bsb[1]).
// (512,2): VGPR cap 128, counted usage ~100 -> no spill (round-2/4 rule).
__global__ __launch_bounds__(512, 2) void gemm_xg(
    const float* __restrict__ x, const unsigned short* __restrict__ B,
    const float* __restrict__ bias, unsigned short* __restrict__ out)
{
    __shared__ alignas(16) unsigned char Bsb[2][32768];  // B bf16 k-major [8][256][16B] x2
    const int tid = threadIdx.x;
    const long long m0 = (long long)blockIdx.x * 64;
    const int l = tid & 63, wv = tid >> 6;               // 8 waves
    const int lane16 = l & 15, quad = l >> 4;
    const int wm = wv & 3, wn = wv >> 2;                 // 4m x 2n waves: 16x128 tiles

    // ---- prologue: A row-quarter into registers (f32 -> bf16) ----
    bf16x8 a_frag[4][2];
    {
        const float* rowp = x + (m0 + wm * 16 + lane16) * 256 + quad * 8;
#pragma unroll
        for (int kt = 0; kt < 4; ++kt)
#pragma unroll
            for (int ks = 0; ks < 2; ++ks) {
                const float* src = rowp + kt * 64 + ks * 32;
                float4 a0 = *(const float4*)src;
                float4 a1 = *(const float4*)(src + 4);
                bf16x8 t;
                t[0] = (__bf16)a0.x; t[1] = (__bf16)a0.y; t[2] = (__bf16)a0.z; t[3] = (__bf16)a0.w;
                t[4] = (__bf16)a1.x; t[5] = (__bf16)a1.y; t[6] = (__bf16)a1.z; t[7] = (__bf16)a1.w;
                a_frag[kt][ks] = t;
            }
    }
    // B tile load: wave wv covers kq=wv, lanes cover rows c*64+l
#define BLOAD(P, KT, BUF)                                                        \
    {                                                                            \
        _Pragma("unroll")                                                        \
        for (int c = 0; c < 4; ++c) {                                            \
            const void* g = (const unsigned char*)B +                            \
                ((size_t)((P) * 256 + c * 64 + l) * 512) + (KT) * 128 + wv * 16; \
            void* d = Bsb[BUF] + wv * 4096 + c * 1024;                           \
            gload_lds16(g, d);                                                   \
        }                                                                        \
    }
    BLOAD(0, 0, 0)

#pragma unroll 1
    for (int p = 0; p < 4; ++p) {
        const int n0 = p * 256;
        v4f acc[8];
#pragma unroll
        for (int b = 0; b < 8; ++b) acc[b] = (v4f){0.f, 0.f, 0.f, 0.f};

#pragma unroll
        for (int kt = 0; kt < 4; ++kt) {
            __syncthreads();          // drains gloads (vmcnt) + syncs all
            if (kt < 3) BLOAD(p, kt + 1, (kt + 1) & 1)   // fly under MFMAs
            const unsigned char* Bcur = Bsb[kt & 1];
#pragma unroll
            for (int ks = 0; ks < 2; ++ks) {
#pragma unroll
                for (int nh = 0; nh < 2; ++nh) {         // nt in halves: caps live regs
                    bf16x8 bfr[4];
#pragma unroll
                    for (int j = 0; j < 4; ++j)
                        bfr[j] = *(const bf16x8*)(Bcur + (ks * 4 + quad) * 4096 +
                                                  (wn * 128 + (nh * 4 + j) * 16 + lane16) * 16);
#pragma unroll
                    for (int j = 0; j < 4; ++j)
                        acc[nh * 4 + j] = __builtin_amdgcn_mfma_f32_16x16x32_bf16(
                            a_frag[kt][ks], bfr[j], acc[nh * 4 + j], 0, 0, 0);
                }
            }
        }

        // ---- epilogue: acc -> Cs (aliases Bsb[1]) -> full-line global stores ----
        float bv[8];
#pragma unroll
        for (int nt = 0; nt < 8; ++nt) bv[nt] = bias[n0 + wn * 128 + nt * 16 + lane16];
        __syncthreads();              // kt3's Bsb[1] reads done
        if (p < 3) BLOAD(p + 1, 0, 0) // next-pass kt0 prefetch flies under epilogue
        unsigned short* Cs = (unsigned short*)Bsb[1];
#pragma unroll
        for (int nt = 0; nt < 8; ++nt)
#pragma unroll
            for (int r = 0; r < 4; ++r) {
                int row = wm * 16 + quad * 4 + r;
                int col = wn * 128 + nt * 16 + lane16;
                Cs[row * 256 + col] = f2bf(acc[nt][r] + bv[nt]);
            }
        __syncthreads();              // Cs complete
#pragma unroll
        for (int i = 0; i < 8; ++i) {
            int g = i * 512 + tid;
            int row = g >> 6, c = g & 63;     // 64 x 8B chunks per 512B row segment
            uint2 v = *(const uint2*)((const unsigned char*)Cs + row * 512 + c * 8);
            *(uint2*)(out + (m0 + row) * 1024 + n0 + c * 4) = v;
        }
    }
#undef BLOAD
}

// ---------------- gemm1: out[t][256] = 2*sigmoid(h2b[t][:] @ fcwbf^T + fcb) ----------
// v6: same template — A row-quarter in registers (bf16 direct, 8x int4 loads),
// B double-buffered k-major LDS via global_load_lds (64KB -> 2 blocks/CU),
// single n-pass. f32 LDS-transpose epilogue (aliases Bsb[0]) in two 32-row
// halves -> full contiguous 1KB-row stores. Accumulation order -> bit-exact.
__global__ __launch_bounds__(512, 2) void gemm_fc(
    const unsigned short* __restrict__ A, const unsigned short* __restrict__ B,
    const float* __restrict__ bias, float* __restrict__ out)
{
    __shared__ alignas(16) unsigned char Bsb[2][32768];  // B bf16 k-major [8][256][16B] x2
    const int tid = threadIdx.x;
    const long long m0 = (long long)blockIdx.x * 64;
    const int l = tid & 63, wv = tid >> 6;
    const int lane16 = l & 15, quad = l >> 4;
    const int wm = wv & 3, wn = wv >> 2;                 // 4m x 2n waves: 16x128 tiles

    // ---- prologue: A row-quarter into registers (already bf16) ----
    bf16x8 a_frag[4][2];
    {
        const unsigned short* rowp = A + (m0 + wm * 16 + lane16) * 256 + quad * 8;
#pragma unroll
        for (int kt = 0; kt < 4; ++kt)
#pragma unroll
            for (int ks = 0; ks < 2; ++ks)
                a_frag[kt][ks] = *(const bf16x8*)(rowp + kt * 64 + ks * 32);
    }
#define BLOADF(KT, BUF)                                                          \
    {                                                                            \
        _Pragma("unroll")                                                        \
        for (int c = 0; c < 4; ++c) {                                            \
            const void* g = (const unsigned char*)B +                            \
                ((size_t)(c * 64 + l) * 512) + (KT) * 128 + wv * 16;             \
            void* d = Bsb[BUF] + wv * 4096 + c * 1024;                           \
            gload_lds16(g, d);                                                   \
        }                                                                        \
    }
    BLOADF(0, 0)

    v4f acc[8];
#pragma unroll
    for (int b = 0; b < 8; ++b) acc[b] = (v4f){0.f, 0.f, 0.f, 0.f};

#pragma unroll
    for (int kt = 0; kt < 4; ++kt) {
        __syncthreads();
        if (kt < 3) BLOADF(kt + 1, (kt + 1) & 1)
        const unsigned char* Bcur = Bsb[kt & 1];
#pragma unroll
        for (int ks = 0; ks < 2; ++ks) {
#pragma unroll
            for (int nh = 0; nh < 2; ++nh) {
                bf16x8 bfr[4];
#pragma unroll
                for (int j = 0; j < 4; ++j)
                    bfr[j] = *(const bf16x8*)(Bcur + (ks * 4 + quad) * 4096 +
                                              (wn * 128 + (nh * 4 + j) * 16 + lane16) * 16);
#pragma unroll
                for (int j = 0; j < 4; ++j)
                    acc[nh * 4 + j] = __builtin_amdgcn_mfma_f32_16x16x32_bf16(
                        a_frag[kt][ks], bfr[j], acc[nh * 4 + j], 0, 0, 0);
            }
        }
    }

    // ---- epilogue: bias + 2*sigmoid -> Csf (f32 [32][256], aliases Bsb[0]) ----
    float bv[8];
#pragma unroll
    for (int nt = 0; nt < 8; ++nt) bv[nt] = bias[wn * 128 + nt * 16 + lane16];
    float* Csf = (float*)Bsb[0];      // kt3 read Bsb[1]; Bsb[0] idle after barrier
#pragma unroll 1
    for (int half = 0; half < 2; ++half) {
        __syncthreads();              // k-loop reads / prev-half Csf reads done
        if ((wm >> 1) == half) {
#pragma unroll
            for (int nt = 0; nt < 8; ++nt)
#pragma unroll
                for (int r = 0; r < 4; ++r) {
                    int lrow = (wm & 1) * 16 + quad * 4 + r;   // 0..31
                    int col = wn * 128 + nt * 16 + lane16;
                    Csf[lrow * 256 + col] = 2.0f * fsig(acc[nt][r] + bv[nt]);
                }
        }
        __syncthreads();              // Csf complete
#pragma unroll
        for (int i = 0; i < 4; ++i) {
            int g = i * 512 + tid;
            int row = g >> 6, c = g & 63;     // 64 int4 chunks per 1KB row
            int4 v = *(const int4*)((const unsigned char*)Csf + row * 1024 + c * 16);
            *(int4*)(out + (m0 + half * 32 + row) * 256 + c * 4) = v;
        }
    }
#undef BLOADF
}

// ---------------- chunked-parallel LSTM scan ----------------
// 256 WGs x 1024 thr. 16 chunks of 16 steps per WG as MFMA columns; burn-in 24.
// W_hh i8 frags in VGPRs; H i8 double-buffered in LDS; xg register-prefetched
// (no clamp: the one-past-end row lands in the h2b workspace region, value
// never consumed); one barrier/step; v_perm-based i8/bf16 packing.
__global__ __launch_bounds__(1024) void lstm_scan(
    const signed char* __restrict__ wfrag, const unsigned short* __restrict__ xg,
    const float* __restrict__ h0, const float* __restrict__ c0,
    unsigned short* __restrict__ h2)
{
    __shared__ alignas(16) signed char Hl[2][16 * 272];
    const int tid = threadIdx.x;
    const int l = tid & 63, wv = tid >> 6;       // wv 0..15
    const int n = l & 15, quad = l >> 4;
    const int wg = blockIdx.x;

    v4i wf[4][4];
#pragma unroll
    for (int tau = 0; tau < 4; ++tau)
#pragma unroll
        for (int kap = 0; kap < 4; ++kap)
            wf[tau][kap] = *(const v4i*)(wfrag + ((((wv * 4 + tau) * 4 + kap) * 64 + l) << 4));

    const int cs0 = (wg * 16 + n) * 16;
    int start = cs0 - 24; if (start < 0) start = 0;
    float cs[4];
#pragma unroll
    for (int tau = 0; tau < 4; ++tau) {
        int u = wv * 16 + tau * 4 + quad;
        cs[tau] = (start == 0) ? c0[u] : 0.f;
    }
    for (int e = tid; e < 4096; e += 1024) {
        int cc = e >> 8, q = e & 255;
        int st = (wg * 16 + cc) * 16 - 24;
        float hv = (st <= 0) ? h0[kperm(q)] : 0.f;
        int qi = (int)rintf(hv * 127.f);
        qi = qi < -127 ? -127 : (qi > 127 ? 127 : qi);
        Hl[0][cc * 272 + q] = (signed char)qi;
    }
    __syncthreads();

    const unsigned short* xbase = xg + wv * 64 + quad * 16;
    int4 xv0, xv1;
    {
        const unsigned short* p = xbase + (long long)start * 1024;
        xv0 = *(const int4*)p;
        xv1 = *(const int4*)(p + 8);
    }

    const float SCL = (0.3f / 127.f) * (1.f / 127.f);
    for (int s = 0; s < 40; ++s) {
        const int cur = s & 1;
        const int t = start + s;
        v4i bfr[4];
#pragma unroll
        for (int kap = 0; kap < 4; ++kap)
            bfr[kap] = *(const v4i*)(Hl[cur] + n * 272 + kap * 64 + quad * 16);

        int4 xn0, xn1;
        {
            const unsigned short* p = xbase + (long long)(t + 1) * 1024;
            xn0 = *(const int4*)p;
            xn1 = *(const int4*)(p + 8);
        }

        const bool wr = ((unsigned)(t - cs0) < 16u);
        unsigned int qlo = 0, qhi = 0;      // packed i8 bytes (pairs)
        unsigned int blo = 0, bhi = 0;      // packed bf16 pairs
        int qprev = 0; float hprev = 0.f;
        int xw[8] = { xv0.x, xv0.y, xv0.z, xv0.w, xv1.x, xv1.y, xv1.z, xv1.w };
#pragma unroll
        for (int tau = 0; tau < 4; ++tau) {
            v4i a = (v4i){0, 0, 0, 0};
#pragma unroll
            for (int kap = 0; kap < 4; ++kap)
                a = __builtin_amdgcn_mfma_i32_16x16x64_i8(wf[tau][kap], bfr[kap], a, 0, 0, 0);
            unsigned int w0 = (unsigned int)xw[tau * 2], w1 = (unsigned int)xw[tau * 2 + 1];
            float gi = fmaf((float)a[0], SCL, asf(w0 << 16));
            float gf = fmaf((float)a[1], SCL, asf(w0 & 0xffff0000u));
            float gg = fmaf((float)a[2], SCL, asf(w1 << 16));
            float go = fmaf((float)a[3], SCL, asf(w1 & 0xffff0000u));
            float ig = fsig(gi), fg = fsig(gf), og = fsig(go), gt = ftanh(gg);
            float cn = fmaf(fg, cs[tau], ig * gt);
            float hn = og * ftanh(cn);
            cs[tau] = cn;
            float qf = fminf(127.f, fmaxf(-127.f, hn * 127.f));
            int qi = (int)rintf(qf);
            if (tau == 0) { qprev = qi; hprev = hn; }
            else if (tau == 1) {
                qlo = __builtin_amdgcn_perm((unsigned int)qi, (unsigned int)qprev, 0x00000400u);
                bf16x2 p; p[0] = (__bf16)hprev; p[1] = (__bf16)hn;
                blo = __builtin_bit_cast(unsigned int, p);
            } else if (tau == 2) { qprev = qi; hprev = hn; }
            else {
                qhi = __builtin_amdgcn_perm((unsigned int)qi, (unsigned int)qprev, 0x04000000u);
                bf16x2 p; p[0] = (__bf16)hprev; p[1] = (__bf16)hn;
                bhi = __builtin_bit_cast(unsigned int, p);
            }
        }
        unsigned int hb = __builtin_amdgcn_perm(qhi, qlo, 0x07060100u);
        *(unsigned int*)(Hl[cur ^ 1] + n * 272 + wv * 16 + quad * 4) = hb;
        if (wr) {
            uint2 hw; hw.x = blo; hw.y = bhi;
            *(uint2*)(h2 + (long long)t * 256 + wv * 16 + quad * 4) = hw;
        }
        __syncthreads();
        xv0 = xn0; xv1 = xn1;
    }
}

extern "C" void kernel_launch(void* const* d_in, const int* in_sizes, int n_in,
                              void* d_out, int out_size, void* d_ws, size_t ws_size,
                              hipStream_t stream)
{
    const float* x    = (const float*)d_in[0];
    const float* Wih2 = (const float*)d_in[7];
    const float* Whh2 = (const float*)d_in[8];
    const float* bih2 = (const float*)d_in[9];
    const float* bhh2 = (const float*)d_in[10];
    const float* h02  = (const float*)d_in[11];
    const float* c02  = (const float*)d_in[12];
    const float* fcW  = (const float*)d_in[13];
    const float* fcb  = (const float*)d_in[14];

    char* ws = (char*)d_ws;
    unsigned short* xgb   = (unsigned short*)(ws);                 // 128 MB xg bf16 [T][1024]
    unsigned short* h2b   = (unsigned short*)(ws + 134217728);     // 32 MB  h2 bf16 [T][256] (k-permuted cols)
    signed char*    w8    = (signed char*)   (ws + 167772160);     // 256 KB W_hh i8 frags
    unsigned short* bperm = (unsigned short*)(ws + 168034304);     // 512 KB W_ih bf16 permuted
    float*          biasp = (float*)         (ws + 168558592);     // 4 KB   fused bias permuted
    unsigned short* fcwbf = (unsigned short*)(ws + 168562688);     // 128 KB fc_W bf16 (k-permuted)

    prep_kernel<<<dim3(1024), dim3(256), 0, stream>>>(
        Wih2, Whh2, bih2, bhh2, fcW, w8, bperm, biasp, fcwbf);

    gemm_xg<<<dim3(1024), dim3(512), 0, stream>>>(x, bperm, biasp, xgb);

    lstm_scan<<<dim3(256), dim3(1024), 0, stream>>>(w8, xgb, h02, c02, h2b);

    gemm_fc<<<dim3(1024), dim3(512), 0, stream>>>(h2b, fcwbf, fcb, (float*)d_out);
}

// Round 8
// 302.086 us; speedup vs baseline: 1.2934x; 1.1403x over previous
//
#include <hip/hip_runtime.h>
#include <cstdint>
#include <cstddef>

typedef int   v4i   __attribute__((ext_vector_type(4)));
typedef float v4f   __attribute__((ext_vector_type(4)));
typedef __bf16 bf16x8 __attribute__((ext_vector_type(8)));
typedef __bf16 bf16x2 __attribute__((ext_vector_type(2)));

__device__ __forceinline__ float bf2f(unsigned short u) {
    union { unsigned int i; float f; } v; v.i = ((unsigned int)u) << 16; return v.f;
}
__device__ __forceinline__ unsigned short f2bf(float f) {
    union { float f; unsigned int i; } v; v.f = f;
    unsigned int r = (v.i + 0x7fffu + ((v.i >> 16) & 1u)) >> 16;
    return (unsigned short)r;
}
__device__ __forceinline__ float asf(unsigned int i) {
    union { unsigned int i; float f; } v; v.i = i; return v.f;
}
__device__ __forceinline__ float fsig(float x) {
    float e = __builtin_amdgcn_exp2f(-1.4426950408889634f * x);
    return __builtin_amdgcn_rcpf(1.0f + e);
}
// tanh(x) = 2*sigmoid(2x)-1 : saturates correctly without clamps
__device__ __forceinline__ float ftanh(float x) {
    float e = __builtin_amdgcn_exp2f(-2.8853900817779268f * x);
    return 2.0f * __builtin_amdgcn_rcpf(1.0f + e) - 1.0f;
}

// Raw barrier with lgkm-only drain: __syncthreads() emits s_waitcnt vmcnt(0)
// lgkmcnt(0) before s_barrier, draining in-flight global prefetches and store
// acks that LDS ordering does not require. This is the verified m201 pattern:
// ds_write -> lgkmcnt(0) -> s_barrier -> ds_read. sched_barrier(0) pins
// against compiler hoisting (guide rule #18).
__device__ __forceinline__ void barrier_lgkm() {
    __builtin_amdgcn_sched_barrier(0);
    asm volatile("s_waitcnt lgkmcnt(0)" ::: "memory");
    __builtin_amdgcn_s_barrier();
    __builtin_amdgcn_sched_barrier(0);
}

#define QW (127.0f / 0.3f)

// k-permutation (involution): swap bits[3:2] <-> bits[1:0] of a 0..255 index
__device__ __forceinline__ int kperm(int k) {
    return (k & ~15) | ((k & 3) << 2) | ((k >> 2) & 3);
}

// ---------------- prep: weight conversions + i8 weight frag packing ----------------
__global__ __launch_bounds__(256) void prep_kernel(
    const float* __restrict__ Wih,
    const float* __restrict__ Whh, const float* __restrict__ bih,
    const float* __restrict__ bhh, const float* __restrict__ fcW,
    signed char* __restrict__ w8,
    unsigned short* __restrict__ bperm, float* __restrict__ biasp,
    unsigned short* __restrict__ fcwbf)
{
    const int NTOT = 262144 + 262144 + 1024 + 65536;
    const int stride = gridDim.x * blockDim.x;
    for (int i = blockIdx.x * blockDim.x + threadIdx.x; i < NTOT; i += stride) {
        if (i < 262144) {
            int t = i;
            int j = t & 15, lane = (t >> 4) & 63, kap = (t >> 10) & 3, tau = (t >> 12) & 3, wv = (t >> 14) & 15;
            int mloc = lane & 15, qm = mloc >> 2, gate = mloc & 3;
            int um = wv * 16 + tau * 4 + qm;
            int kpos = kap * 64 + (lane >> 4) * 16 + j;
            int uk = kperm(kpos);
            float val = Whh[(gate * 256 + um) * 256 + uk];
            int qi = (int)rintf(val * QW);
            qi = qi < -127 ? -127 : (qi > 127 ? 127 : qi);
            w8[t] = (signed char)qi;
        } else if (i < 524288) {
            int t = i - 262144;
            int nn = t >> 8, k = t & 255;
            int gate = nn & 3, tau = (nn >> 2) & 3, quad = (nn >> 4) & 3, wv = nn >> 6;
            int u = wv * 16 + tau * 4 + quad;
            bperm[t] = f2bf(Wih[(gate * 256 + u) * 256 + k]);
        } else if (i < 524288 + 1024) {
            int nn = i - 524288;
            int gate = nn & 3, tau = (nn >> 2) & 3, quad = (nn >> 4) & 3, wv = nn >> 6;
            int u = wv * 16 + tau * 4 + quad;
            biasp[nn] = bih[gate * 256 + u] + bhh[gate * 256 + u];
        } else {
            int t = i - (524288 + 1024);
            int n = t >> 8, k = t & 255;
            fcwbf[t] = f2bf(fcW[n * 256 + kperm(k)]);
        }
    }
}

// ---------------- gemm0: xg[t][1024] = x[t][:] @ bperm^T + biasp, bf16 out ----------
// v3 + lgkm-only barriers: 64-row m-tiles (1024 blocks), each block computes
// ALL 4 n-passes. A-tile loaded from HBM once (pass 0) and persisted in regs;
// passes 1-3 restage LDS from regs -> x fetched exactly once. Epilogue goes
// through an LDS tile so global stores are full 512B row segments; barriers
// no longer drain C-store acks. NOTE: (512,4) caps VGPR at 64 -> NO register
// prefetch fits here (round-2/4 spill regressions).
__global__ __launch_bounds__(512, 4) void gemm_xg(
    const float* __restrict__ x, const unsigned short* __restrict__ B,
    const float* __restrict__ bias, unsigned short* __restrict__ out)
{
    __shared__ alignas(16) unsigned short S[23040];   // As[64*72] | Bs[256*72]; Cs[64*264] aliases
    unsigned short* As = S;
    unsigned short* Bs = S + 4608;
    unsigned short* Cs = S;
    const int tid = threadIdx.x;
    const long long m0 = (long long)blockIdx.x * 64;
    const int l = tid & 63, wv = tid >> 6;
    const int lane16 = l & 15, quad = l >> 4;
    const int wm = wv & 1, wn = wv >> 1;              // 2m x 4n waves: 32x64 tiles

    const int arow = tid >> 3, ac8 = tid & 7;          // A staging: 1 float8 / thread
    bf16x8 a_save[4];

#pragma unroll 1
    for (int p = 0; p < 4; ++p) {
        const int n0 = p * 256;
        v4f acc[2][4];
#pragma unroll
        for (int a = 0; a < 2; ++a)
#pragma unroll
            for (int b = 0; b < 4; ++b) acc[a][b] = (v4f){0.f, 0.f, 0.f, 0.f};

#pragma unroll
        for (int kt = 0; kt < 4; ++kt) {
            barrier_lgkm();           // LDS free (prev compute / epilogue done)
            if (p == 0) {
                const float* src = x + (m0 + arow) * 256 + kt * 64 + ac8 * 8;
                float4 a0 = *(const float4*)src;
                float4 a1 = *(const float4*)(src + 4);
                bf16x8 t;
                t[0] = (__bf16)a0.x; t[1] = (__bf16)a0.y; t[2] = (__bf16)a0.z; t[3] = (__bf16)a0.w;
                t[4] = (__bf16)a1.x; t[5] = (__bf16)a1.y; t[6] = (__bf16)a1.z; t[7] = (__bf16)a1.w;
                a_save[kt] = t;
                *(bf16x8*)(As + arow * 72 + ac8 * 8) = t;
            } else {
                *(bf16x8*)(As + arow * 72 + ac8 * 8) = a_save[kt];
            }
#pragma unroll
            for (int r = 0; r < 4; ++r) {
                int j = tid * 4 + r;
                int brow = j >> 3, bc8 = j & 7;
                *(int4*)(Bs + brow * 72 + bc8 * 8) =
                    *(const int4*)(B + (long long)(n0 + brow) * 256 + kt * 64 + bc8 * 8);
            }
            barrier_lgkm();           // tile ready
#pragma unroll
            for (int ks = 0; ks < 2; ++ks) {
                bf16x8 af[2], bfr[4];
#pragma unroll
                for (int mt = 0; mt < 2; ++mt)
                    af[mt] = *(const bf16x8*)(As + (wm * 32 + mt * 16 + lane16) * 72 + ks * 32 + quad * 8);
#pragma unroll
                for (int nt = 0; nt < 4; ++nt)
                    bfr[nt] = *(const bf16x8*)(Bs + (wn * 64 + nt * 16 + lane16) * 72 + ks * 32 + quad * 8);
#pragma unroll
                for (int mt = 0; mt < 2; ++mt)
#pragma unroll
                    for (int nt = 0; nt < 4; ++nt)
                        acc[mt][nt] = __builtin_amdgcn_mfma_f32_16x16x32_bf16(af[mt], bfr[nt], acc[mt][nt], 0, 0, 0);
            }
        }

        // ---- epilogue: acc -> Cs (bf16, bank-clean) -> full-row global stores ----
        float bv[4];
#pragma unroll
        for (int nt = 0; nt < 4; ++nt) bv[nt] = bias[n0 + wn * 64 + nt * 16 + lane16];
        barrier_lgkm();               // k-loop LDS reads done; Cs may alias As/Bs
#pragma unroll
        for (int mt = 0; mt < 2; ++mt)
#pragma unroll
            for (int nt = 0; nt < 4; ++nt)
#pragma unroll
                for (int r = 0; r < 4; ++r) {
                    int row = wm * 32 + mt * 16 + quad * 4 + r;
                    int col = wn * 64 + nt * 16 + lane16;
                    Cs[row * 264 + col] = f2bf(acc[mt][nt][r] + bv[nt]);
                }
        barrier_lgkm();               // Cs complete
#pragma unroll
        for (int i = 0; i < 8; ++i) {
            int g = i * 512 + tid;
            int row = g >> 6, c = g & 63;     // 64 x 8B chunks per 512B row segment
            uint2 v = *(const uint2*)(Cs + row * 264 + c * 4);
            *(uint2*)(out + (m0 + row) * 1024 + n0 + c * 4) = v;
        }
        // next pass's first barrier_lgkm protects Cs reads before restaging
    }
}

// ---------------- gemm1: out[t][256] = 2*sigmoid(h2b[t][:] @ fcwbf^T + fcb) ----------
// v4 + lgkm-only barriers: 64-row blocks x full 256-col rows (1024 blocks),
// NO register prefetch (spill-safe). Per-kt LDS staging straight from global;
// f32 LDS-transpose epilogue in two 32-row half-passes -> every global store
// is a full contiguous 1KB row. Accumulation order kt x ks -> bit-exact.
__global__ __launch_bounds__(512) void gemm_fc(
    const unsigned short* __restrict__ A, const unsigned short* __restrict__ B,
    const float* __restrict__ bias, float* __restrict__ out)
{
    __shared__ alignas(16) unsigned short S[23040];   // As[64*72] | Bs[256*72]; Csf[32*268] f32 aliases
    unsigned short* As = S;
    unsigned short* Bs = S + 4608;
    float* Csf = (float*)S;
    const int tid = threadIdx.x;
    const long long m0 = (long long)blockIdx.x * 64;
    const int l = tid & 63, wv = tid >> 6;
    const int lane16 = l & 15, quad = l >> 4;
    const int wm = wv & 1, wn = wv >> 1;              // 2m x 4n waves: 32x64 tiles

    const int arow = tid >> 3, ac8 = tid & 7;

    v4f acc[2][4];
#pragma unroll
    for (int a = 0; a < 2; ++a)
#pragma unroll
        for (int b = 0; b < 4; ++b) acc[a][b] = (v4f){0.f, 0.f, 0.f, 0.f};

#pragma unroll
    for (int kt = 0; kt < 4; ++kt) {
        barrier_lgkm();
        *(int4*)(As + arow * 72 + ac8 * 8) =
            *(const int4*)(A + (m0 + arow) * 256 + kt * 64 + ac8 * 8);
#pragma unroll
        for (int r = 0; r < 4; ++r) {
            int j = tid * 4 + r;
            int br = j >> 3, bc = j & 7;
            *(int4*)(Bs + br * 72 + bc * 8) =
                *(const int4*)(B + (long long)br * 256 + kt * 64 + bc * 8);
        }
        barrier_lgkm();
#pragma unroll
        for (int ks = 0; ks < 2; ++ks) {
            bf16x8 af[2], bfr[4];
#pragma unroll
            for (int mt = 0; mt < 2; ++mt)
                af[mt] = *(const bf16x8*)(As + (wm * 32 + mt * 16 + lane16) * 72 + ks * 32 + quad * 8);
#pragma unroll
            for (int nt = 0; nt < 4; ++nt)
                bfr[nt] = *(const bf16x8*)(Bs + (wn * 64 + nt * 16 + lane16) * 72 + ks * 32 + quad * 8);
#pragma unroll
            for (int mt = 0; mt < 2; ++mt)
#pragma unroll
                for (int nt = 0; nt < 4; ++nt)
                    acc[mt][nt] = __builtin_amdgcn_mfma_f32_16x16x32_bf16(af[mt], bfr[nt], acc[mt][nt], 0, 0, 0);
        }
    }

    // ---- epilogue: bias + 2*sigmoid -> Csf (f32, stride 268) -> full 1KB row stores ----
    float bv[4];
#pragma unroll
    for (int nt = 0; nt < 4; ++nt) bv[nt] = bias[wn * 64 + nt * 16 + lane16];
#pragma unroll 1
    for (int half = 0; half < 2; ++half) {
        barrier_lgkm();               // k-loop LDS reads / prev-half Csf reads done
        if (wm == half) {
#pragma unroll
            for (int mt = 0; mt < 2; ++mt)
#pragma unroll
                for (int nt = 0; nt < 4; ++nt)
#pragma unroll
                    for (int r = 0; r < 4; ++r) {
                        int row = mt * 16 + quad * 4 + r;          // 0..31
                        int col = wn * 64 + nt * 16 + lane16;
                        Csf[row * 268 + col] = 2.0f * fsig(acc[mt][nt][r] + bv[nt]);
                    }
        }
        barrier_lgkm();               // Csf complete
#pragma unroll
        for (int i = 0; i < 4; ++i) {
            int g = i * 512 + tid;
            int row = g >> 6, c = g & 63;     // 64 int4 chunks per 1KB row
            int4 v = *(const int4*)(Csf + row * 268 + c * 4);
            *(int4*)(out + (m0 + half * 32 + row) * 256 + c * 4) = v;
        }
    }
}

// ---------------- chunked-parallel LSTM scan ----------------
// 256 WGs x 1024 thr. 16 chunks of 16 steps per WG as MFMA columns; burn-in 24.
// W_hh i8 frags in VGPRs; H i8 double-buffered in LDS; xg register-prefetched;
// ONE lgkm-only barrier/step: the xg prefetch and h2 store acks fly across the
// barrier instead of being drained by __syncthreads' vmcnt(0) every step.
__global__ __launch_bounds__(1024) void lstm_scan(
    const signed char* __restrict__ wfrag, const unsigned short* __restrict__ xg,
    const float* __restrict__ h0, const float* __restrict__ c0,
    unsigned short* __restrict__ h2)
{
    __shared__ alignas(16) signed char Hl[2][16 * 272];
    const int tid = threadIdx.x;
    const int l = tid & 63, wv = tid >> 6;       // wv 0..15
    const int n = l & 15, quad = l >> 4;
    const int wg = blockIdx.x;

    v4i wf[4][4];
#pragma unroll
    for (int tau = 0; tau < 4; ++tau)
#pragma unroll
        for (int kap = 0; kap < 4; ++kap)
            wf[tau][kap] = *(const v4i*)(wfrag + ((((wv * 4 + tau) * 4 + kap) * 64 + l) << 4));

    const int cs0 = (wg * 16 + n) * 16;
    int start = cs0 - 24; if (start < 0) start = 0;
    float cs[4];
#pragma unroll
    for (int tau = 0; tau < 4; ++tau) {
        int u = wv * 16 + tau * 4 + quad;
        cs[tau] = (start == 0) ? c0[u] : 0.f;
    }
    for (int e = tid; e < 4096; e += 1024) {
        int cc = e >> 8, q = e & 255;
        int st = (wg * 16 + cc) * 16 - 24;
        float hv = (st <= 0) ? h0[kperm(q)] : 0.f;
        int qi = (int)rintf(hv * 127.f);
        qi = qi < -127 ? -127 : (qi > 127 ? 127 : qi);
        Hl[0][cc * 272 + q] = (signed char)qi;
    }
    barrier_lgkm();

    const unsigned short* xbase = xg + wv * 64 + quad * 16;
    int4 xv0, xv1;
    {
        const unsigned short* p = xbase + (long long)start * 1024;
        xv0 = *(const int4*)p;
        xv1 = *(const int4*)(p + 8);
    }

    const float SCL = (0.3f / 127.f) * (1.f / 127.f);
    for (int s = 0; s < 40; ++s) {
        const int cur = s & 1;
        const int t = start + s;
        v4i bfr[4];
#pragma unroll
        for (int kap = 0; kap < 4; ++kap)
            bfr[kap] = *(const v4i*)(Hl[cur] + n * 272 + kap * 64 + quad * 16);

        int4 xn0, xn1;
        {
            const unsigned short* p = xbase + (long long)(t + 1) * 1024;
            xn0 = *(const int4*)p;
            xn1 = *(const int4*)(p + 8);
        }

        const bool wr = ((unsigned)(t - cs0) < 16u);
        unsigned int qlo = 0, qhi = 0;      // packed i8 bytes (pairs)
        unsigned int blo = 0, bhi = 0;      // packed bf16 pairs
        int qprev = 0; float hprev = 0.f;
        int xw[8] = { xv0.x, xv0.y, xv0.z, xv0.w, xv1.x, xv1.y, xv1.z, xv1.w };
#pragma unroll
        for (int tau = 0; tau < 4; ++tau) {
            v4i a = (v4i){0, 0, 0, 0};
#pragma unroll
            for (int kap = 0; kap < 4; ++kap)
                a = __builtin_amdgcn_mfma_i32_16x16x64_i8(wf[tau][kap], bfr[kap], a, 0, 0, 0);
            unsigned int w0 = (unsigned int)xw[tau * 2], w1 = (unsigned int)xw[tau * 2 + 1];
            float gi = fmaf((float)a[0], SCL, asf(w0 << 16));
            float gf = fmaf((float)a[1], SCL, asf(w0 & 0xffff0000u));
            float gg = fmaf((float)a[2], SCL, asf(w1 << 16));
            float go = fmaf((float)a[3], SCL, asf(w1 & 0xffff0000u));
            float ig = fsig(gi), fg = fsig(gf), og = fsig(go), gt = ftanh(gg);
            float cn = fmaf(fg, cs[tau], ig * gt);
            float hn = og * ftanh(cn);
            cs[tau] = cn;
            float qf = fminf(127.f, fmaxf(-127.f, hn * 127.f));
            int qi = (int)rintf(qf);
            if (tau == 0) { qprev = qi; hprev = hn; }
            else if (tau == 1) {
                qlo = __builtin_amdgcn_perm((unsigned int)qi, (unsigned int)qprev, 0x00000400u);
                bf16x2 p; p[0] = (__bf16)hprev; p[1] = (__bf16)hn;
                blo = __builtin_bit_cast(unsigned int, p);
            } else if (tau == 2) { qprev = qi; hprev = hn; }
            else {
                qhi = __builtin_amdgcn_perm((unsigned int)qi, (unsigned int)qprev, 0x04000000u);
                bf16x2 p; p[0] = (__bf16)hprev; p[1] = (__bf16)hn;
                bhi = __builtin_bit_cast(unsigned int, p);
            }
        }
        unsigned int hb = __builtin_amdgcn_perm(qhi, qlo, 0x07060100u);
        *(unsigned int*)(Hl[cur ^ 1] + n * 272 + wv * 16 + quad * 4) = hb;
        if (wr) {
            uint2 hw; hw.x = blo; hw.y = bhi;
            *(uint2*)(h2 + (long long)t * 256 + wv * 16 + quad * 4) = hw;
        }
        barrier_lgkm();               // lgkm-only: xg prefetch + h2 stores fly across
        xv0 = xn0; xv1 = xn1;
    }
}

extern "C" void kernel_launch(void* const* d_in, const int* in_sizes, int n_in,
                              void* d_out, int out_size, void* d_ws, size_t ws_size,
                              hipStream_t stream)
{
    const float* x    = (const float*)d_in[0];
    const float* Wih2 = (const float*)d_in[7];
    const float* Whh2 = (const float*)d_in[8];
    const float* bih2 = (const float*)d_in[9];
    const float* bhh2 = (const float*)d_in[10];
    const float* h02  = (const float*)d_in[11];
    const float* c02  = (const float*)d_in[12];
    const float* fcW  = (const float*)d_in[13];
    const float* fcb  = (const float*)d_in[14];

    char* ws = (char*)d_ws;
    unsigned short* xgb   = (unsigned short*)(ws);                 // 128 MB xg bf16 [T][1024]
    unsigned short* h2b   = (unsigned short*)(ws + 134217728);     // 32 MB  h2 bf16 [T][256] (k-permuted cols)
    signed char*    w8    = (signed char*)   (ws + 167772160);     // 256 KB W_hh i8 frags
    unsigned short* bperm = (unsigned short*)(ws + 168034304);     // 512 KB W_ih bf16 permuted
    float*          biasp = (float*)         (ws + 168558592);     // 4 KB   fused bias permuted
    unsigned short* fcwbf = (unsigned short*)(ws + 168562688);     // 128 KB fc_W bf16 (k-permuted)

    prep_kernel<<<dim3(1024), dim3(256), 0, stream>>>(
        Wih2, Whh2, bih2, bhh2, fcW, w8, bperm, biasp, fcwbf);

    gemm_xg<<<dim3(1024), dim3(512), 0, stream>>>(x, bperm, biasp, xgb);

    lstm_scan<<<dim3(256), dim3(1024), 0, stream>>>(w8, xgb, h02, c02, h2b);

    gemm_fc<<<dim3(1024), dim3(512), 0, stream>>>(h2b, fcwbf, fcb, (float*)d_out);
}